// Round 2
// baseline (368.575 us; speedup 1.0000x reference)
//
#include <hip/hip_runtime.h>
#include <hip/hip_bf16.h>

namespace {

constexpr int kB = 256;
constexpr int kS = 512;
constexpr int kJ = 22;
constexpr int CHUNK  = 30;                        // useful frames per wave (32 lane-pairs, 2 overlap)
constexpr int NCHUNK = (kS + CHUNK - 1) / CHUNK;  // 18
constexpr int NACC  = 9;
constexpr int NSLOT = 64;                         // atomic spreading

__device__ __forceinline__ void cont6d(const float a[6], float R[3][3]) {
    float n1 = sqrtf(a[0]*a[0] + a[1]*a[1] + a[2]*a[2]);
    float i1 = 1.0f / fmaxf(n1, 1e-12f);
    float b1x = a[0]*i1, b1y = a[1]*i1, b1z = a[2]*i1;
    float dp  = b1x*a[3] + b1y*a[4] + b1z*a[5];
    float ux = a[3] - b1x*dp, uy = a[4] - b1y*dp, uz = a[5] - b1z*dp;
    float n2 = sqrtf(ux*ux + uy*uy + uz*uz);
    float i2 = 1.0f / fmaxf(n2, 1e-12f);
    float b2x = ux*i2, b2y = uy*i2, b2z = uz*i2;
    R[0][0] = b1x; R[1][0] = b1y; R[2][0] = b1z;
    R[0][1] = b2x; R[1][1] = b2y; R[2][1] = b2z;
    R[0][2] = b1y*b2z - b1z*b2y;
    R[1][2] = b1z*b2x - b1x*b2z;
    R[2][2] = b1x*b2y - b1y*b2x;
}

// One FK joint for ONE skeleton (this lane's tensor). Pair partner (lane^1)
// holds the other skeleton; diffs via shfl_xor(.,1). Frame s+1 is at lane+2,
// s+2 at lane+4 (shfl_down).
template<bool NEED_R, bool SPINE_J, bool FOOT>
__device__ __forceinline__ void joint_step(
    const float* __restrict__ jd, const float* __restrict__ off,
    const float Rp[3][3], const float pp[3],
    float Rn[3][3], float pn[3],
    float wf, float wv, float wa, float wc,
    float& s_raw, float& spos, float& svel, float& ssmo,
    float& stil, float& sflo, float& scon)
{
    const float2* q = reinterpret_cast<const float2*>(jd);
    float2 q0 = q[0], q1 = q[1], q2 = q[2];
    float a[6] = {q0.x, q0.y, q1.x, q1.y, q2.x, q2.y};

    // raw-channel loss (pred-targ across the lane pair)
    float dsum = 0.f;
    #pragma unroll
    for (int k = 0; k < 6; ++k) { float d = a[k] - __shfl_xor(a[k], 1); dsum += d*d; }
    s_raw += wf * dsum;

    // position: pn = pp + Rp @ off   (parent rotation, not own)
    const float ox = off[0], oy = off[1], oz = off[2];
    #pragma unroll
    for (int r = 0; r < 3; ++r)
        pn[r] = pp[r] + Rp[r][0]*ox + Rp[r][1]*oy + Rp[r][2]*oz;

    if constexpr (NEED_R) {
        float Rl[3][3];
        cont6d(a, Rl);
        if constexpr (SPINE_J) { // tilt: local b2 column
            float t0 = Rl[0][1] - __shfl_xor(Rl[0][1], 1);
            float t1 = Rl[1][1] - __shfl_xor(Rl[1][1], 1);
            float t2 = Rl[2][1] - __shfl_xor(Rl[2][1], 1);
            stil += wf * (t0*t0 + t1*t1 + t2*t2);
        }
        #pragma unroll
        for (int r = 0; r < 3; ++r)
            #pragma unroll
            for (int c = 0; c < 3; ++c)
                Rn[r][c] = Rp[r][0]*Rl[0][c] + Rp[r][1]*Rl[1][c] + Rp[r][2]*Rl[2][c];
    }

    // pos / vel / smooth (d = own - partner; square is parity-invariant)
    float d[3];
    #pragma unroll
    for (int r = 0; r < 3; ++r) d[r] = pn[r] - __shfl_xor(pn[r], 1);
    spos += wf * (d[0]*d[0] + d[1]*d[1] + d[2]*d[2]);

    float va = 0.f, sa = 0.f;
    #pragma unroll
    for (int r = 0; r < 3; ++r) {
        float d1 = __shfl_down(d[r], 2);
        float d2 = __shfl_down(d[r], 4);
        float dv = d1 - d[r];            va += dv*dv;
        float ds = d2 - 2.f*d1 + d[r];   sa += ds*ds;
    }
    svel += wv * va;
    ssmo += wa * sa;

    if constexpr (FOOT) {
        sflo += wf * d[1]*d[1];          // y-component
        float vx = __shfl_down(pn[0], 2) - pn[0];   // own-tensor velocity
        float vy = __shfl_down(pn[1], 2) - pn[1];
        float vz = __shfl_down(pn[2], 2) - pn[2];
        float gx = __shfl_xor(vx, 1);                // partner (gt on even lanes)
        float gy = __shfl_xor(vy, 1);
        float gz = __shfl_xor(vz, 1);
        float gn2 = gx*gx + gy*gy + gz*gz;
        float planted = (gn2 < 2.5e-5f) ? 1.f : 0.f; // (0.005)^2
        scon += wc * planted * sqrtf(vx*vx + vy*vy + vz*vz);
    }
}

__global__ __launch_bounds__(64, 4)
void motion_loss_kernel(const float* __restrict__ pred,
                        const float* __restrict__ targ,
                        const float* __restrict__ offs,
                        float* __restrict__ acc)
{
    const int lane = threadIdx.x;       // 0..63
    const int fid  = lane >> 1;         // frame-in-chunk 0..31
    const int par  = lane & 1;          // 0 = pred, 1 = targ
    const int bid  = blockIdx.x;
    const int b    = bid / NCHUNK;
    const int chunk= bid - b * NCHUNK;
    const int s    = chunk * CHUNK + fid;
    const int sc   = (s < kS) ? s : (kS - 1);

    const float wf = (fid < CHUNK && s     < kS) ? 1.f : 0.f;
    const float wv = (fid < CHUNK && s + 1 < kS) ? 1.f : 0.f;
    const float wa = (fid < CHUNK && s + 2 < kS) ? 1.f : 0.f;
    const float wc = (par == 0) ? wv : 0.f;   // contact counted once per frame

    const float* base = (par ? targ : pred) + ((size_t)b * kS + sc) * (kJ * 6);

    float sr1=0.f, sr2=0.f, srot=0.f, spos=0.f, svel=0.f,
          ssmo=0.f, sflo=0.f, scon=0.f, stil=0.f;

    { // joint 0: channels 0..2 only; position is identically 0 for both skeletons
        float2 r01 = *reinterpret_cast<const float2*>(base);
        float  r2  = base[2];
        float d0 = r01.x - __shfl_xor(r01.x, 1);
        float d1 = r01.y - __shfl_xor(r01.y, 1);
        float d2 = r2    - __shfl_xor(r2, 1);
        sr1 = wf * (d0*d0 + d1*d1 + d2*d2);
    }

    float R1[3][3], R3[3][3], RA[3][3], RB[3][3];
    float p1[3], p3[3], pA[3], pB[3];

    { // joint 1: parent = identity; pos = offs[1] for BOTH skeletons → pos losses 0
        const float2* q = reinterpret_cast<const float2*>(base + 6);
        float2 q0 = q[0], q1 = q[1], q2 = q[2];
        float a[6] = {q0.x, q0.y, q1.x, q1.y, q2.x, q2.y};
        float dsum = 0.f;
        #pragma unroll
        for (int k = 0; k < 6; ++k) { float d = a[k] - __shfl_xor(a[k], 1); dsum += d*d; }
        sr2 = wf * dsum;
        cont6d(a, R1);
        p1[0] = offs[3]; p1[1] = offs[4]; p1[2] = offs[5];
    }

    // chain order; live set: R1 (until j19), R3 (until j10), RA/RB ping-pong
    joint_step<true ,true ,false>(base+2*6 , offs+2*3 , R1, p1, RA, pA, wf,wv,wa,wc, srot,spos,svel,ssmo,stil,sflo,scon); // j2 (spine)
    joint_step<true ,false,false>(base+3*6 , offs+3*3 , RA, pA, R3, p3, wf,wv,wa,wc, srot,spos,svel,ssmo,stil,sflo,scon); // j3
    joint_step<true ,false,false>(base+4*6 , offs+4*3 , R3, p3, RA, pA, wf,wv,wa,wc, srot,spos,svel,ssmo,stil,sflo,scon); // j4
    joint_step<false,false,false>(base+5*6 , offs+5*3 , RA, pA, RB, pB, wf,wv,wa,wc, srot,spos,svel,ssmo,stil,sflo,scon); // j5 leaf
    joint_step<true ,false,false>(base+6*6 , offs+6*3 , R3, p3, RA, pA, wf,wv,wa,wc, srot,spos,svel,ssmo,stil,sflo,scon); // j6
    joint_step<true ,false,false>(base+7*6 , offs+7*3 , RA, pA, RB, pB, wf,wv,wa,wc, srot,spos,svel,ssmo,stil,sflo,scon); // j7
    joint_step<true ,false,false>(base+8*6 , offs+8*3 , RB, pB, RA, pA, wf,wv,wa,wc, srot,spos,svel,ssmo,stil,sflo,scon); // j8
    joint_step<false,false,false>(base+9*6 , offs+9*3 , RA, pA, RB, pB, wf,wv,wa,wc, srot,spos,svel,ssmo,stil,sflo,scon); // j9 leaf
    joint_step<true ,false,false>(base+10*6, offs+10*3, R3, p3, RA, pA, wf,wv,wa,wc, srot,spos,svel,ssmo,stil,sflo,scon); // j10 (R3 dies)
    joint_step<true ,false,false>(base+11*6, offs+11*3, RA, pA, RB, pB, wf,wv,wa,wc, srot,spos,svel,ssmo,stil,sflo,scon); // j11
    joint_step<true ,false,false>(base+12*6, offs+12*3, RB, pB, RA, pA, wf,wv,wa,wc, srot,spos,svel,ssmo,stil,sflo,scon); // j12
    joint_step<false,false,false>(base+13*6, offs+13*3, RA, pA, RB, pB, wf,wv,wa,wc, srot,spos,svel,ssmo,stil,sflo,scon); // j13 leaf
    joint_step<true ,false,false>(base+14*6, offs+14*3, R1, p1, RA, pA, wf,wv,wa,wc, srot,spos,svel,ssmo,stil,sflo,scon); // j14
    joint_step<true ,false,false>(base+15*6, offs+15*3, RA, pA, RB, pB, wf,wv,wa,wc, srot,spos,svel,ssmo,stil,sflo,scon); // j15
    joint_step<true ,false,false>(base+16*6, offs+16*3, RB, pB, RA, pA, wf,wv,wa,wc, srot,spos,svel,ssmo,stil,sflo,scon); // j16
    joint_step<true ,false,false>(base+17*6, offs+17*3, RA, pA, RB, pB, wf,wv,wa,wc, srot,spos,svel,ssmo,stil,sflo,scon); // j17
    joint_step<false,false,true >(base+18*6, offs+18*3, RB, pB, RA, pA, wf,wv,wa,wc, srot,spos,svel,ssmo,stil,sflo,scon); // j18 FOOT leaf
    joint_step<true ,false,false>(base+19*6, offs+19*3, R1, p1, RA, pA, wf,wv,wa,wc, srot,spos,svel,ssmo,stil,sflo,scon); // j19 (R1 dies)
    joint_step<true ,false,false>(base+20*6, offs+20*3, RA, pA, RB, pB, wf,wv,wa,wc, srot,spos,svel,ssmo,stil,sflo,scon); // j20
    joint_step<false,false,true >(base+21*6, offs+21*3, RB, pB, RA, pA, wf,wv,wa,wc, srot,spos,svel,ssmo,stil,sflo,scon); // j21 FOOT leaf

    // wave butterfly reduce; one atomic per sum per wave, spread over 64 slots
    float vals[NACC] = {sr1, sr2, srot, spos, svel, ssmo, sflo, scon, stil};
    #pragma unroll
    for (int k = 0; k < NACC; ++k) {
        float v = vals[k];
        #pragma unroll
        for (int o = 32; o > 0; o >>= 1) v += __shfl_xor(v, o);
        if (lane == 0) atomicAdd(&acc[k * NSLOT + (bid & (NSLOT - 1))], v);
    }
}

__global__ void finalize_kernel(const float* __restrict__ acc, float* __restrict__ out) {
    const int lane = threadIdx.x;
    float v = 0.f;
    if (lane < NACC) {
        #pragma unroll 8
        for (int j = 0; j < NSLOT; ++j) v += acc[lane * NSLOT + j];
    }
    __shared__ float r[NACC];
    if (lane < NACC) r[lane] = v;
    __syncthreads();
    if (lane == 0) {
        const float BS = (float)kB * (float)kS;      // 131072
        // every non-contact sum is accumulated by BOTH lane parities → 2×
        float total = 5.0f * (r[0] / (2.f*BS*3.f)  + r[1] / (2.f*BS*6.f))
                    + 1.0f * (r[2] / (2.f*BS*120.f))
                    + 2.0f * (r[3] / (2.f*BS*66.f))
                    + 1.0f * (r[4] / (2.f*(float)kB*(float)(kS-1)*66.f))
                    + 0.5f * (r[5] / (2.f*(float)kB*(float)(kS-2)*66.f))
                    + 2.0f * (r[6] / (2.f*BS*2.f))
                    + 2.0f * (r[7] / ((float)kB*(float)(kS-1)*2.f))
                    + 1.0f * (r[8] / (2.f*BS*3.f));
        out[0] = total;
    }
}

} // namespace

extern "C" void kernel_launch(void* const* d_in, const int* in_sizes, int n_in,
                              void* d_out, int out_size, void* d_ws, size_t ws_size,
                              hipStream_t stream) {
    const float* pred = (const float*)d_in[0];
    const float* targ = (const float*)d_in[1];
    const float* offs = (const float*)d_in[2];
    float* acc = (float*)d_ws;

    hipMemsetAsync(acc, 0, NACC * NSLOT * sizeof(float), stream);
    motion_loss_kernel<<<dim3(kB * NCHUNK), dim3(64), 0, stream>>>(pred, targ, offs, acc);
    finalize_kernel<<<1, 64, 0, stream>>>(acc, (float*)d_out);
}

// Round 3
// 142.648 us; speedup vs baseline: 2.5838x; 2.5838x over previous
//
#include <hip/hip_runtime.h>

namespace {

constexpr int kB = 256;
constexpr int kS = 512;
constexpr int CHUNK  = 30;                        // useful frames per wave (32 lane-pairs, 2 overlap)
constexpr int NCHUNK = (kS + CHUNK - 1) / CHUNK;  // 18
constexpr int NSLOT  = 64;

// ---- pre-scaled loss weights (lambda / count), non-contact terms counted by BOTH parities (2x)
constexpr float BSf  = 131072.f;                  // kB*kS
constexpr float K_R1  = 5.0f / (2.f * BSf * 3.f);
constexpr float K_R2  = 5.0f / (2.f * BSf * 6.f);
constexpr float K_ROT = 1.0f / (2.f * BSf * 120.f);
constexpr float K_POS = 2.0f / (2.f * BSf * 66.f);
constexpr float K_VEL = 1.0f / (2.f * 256.f * 511.f * 66.f);
constexpr float K_SMO = 0.5f / (2.f * 256.f * 510.f * 66.f);
constexpr float K_FLO = 2.0f / (2.f * BSf * 2.f);
constexpr float K_CON = 2.0f / (256.f * 511.f * 2.f);   // contact: even lanes only (no 2x)
constexpr float K_TIL = 1.0f / (2.f * BSf * 3.f);

__device__ __forceinline__ void cont6d(const float a[6], float R[3][3]) {
    float n1 = sqrtf(a[0]*a[0] + a[1]*a[1] + a[2]*a[2]);
    float i1 = 1.0f / fmaxf(n1, 1e-12f);
    float b1x = a[0]*i1, b1y = a[1]*i1, b1z = a[2]*i1;
    float dp  = b1x*a[3] + b1y*a[4] + b1z*a[5];
    float ux = a[3] - b1x*dp, uy = a[4] - b1y*dp, uz = a[5] - b1z*dp;
    float n2 = sqrtf(ux*ux + uy*uy + uz*uz);
    float i2 = 1.0f / fmaxf(n2, 1e-12f);
    float b2x = ux*i2, b2y = uy*i2, b2z = uz*i2;
    R[0][0] = b1x; R[1][0] = b1y; R[2][0] = b1z;
    R[0][1] = b2x; R[1][1] = b2y; R[2][1] = b2z;
    R[0][2] = b1y*b2z - b1z*b2y;
    R[1][2] = b1z*b2x - b1x*b2z;
    R[2][2] = b1x*b2y - b1y*b2x;
}

// frame data register file: floats [0..63] in A, [64..65] tA, [66..67] tB, [68..131] in Bv
template<int F>
__device__ __forceinline__ float getf(const float4 (&A)[16], const float2& tA,
                                      const float2& tB, const float4 (&Bv)[16]) {
    if constexpr (F < 64) {
        constexpr int k = F >> 2, c = F & 3;
        if constexpr (c == 0) return A[k].x; else if constexpr (c == 1) return A[k].y;
        else if constexpr (c == 2) return A[k].z; else return A[k].w;
    } else if constexpr (F == 64) { return tA.x;
    } else if constexpr (F == 65) { return tA.y;
    } else if constexpr (F == 66) { return tB.x;
    } else if constexpr (F == 67) { return tB.y;
    } else {
        constexpr int G = F - 68, k = G >> 2, c = G & 3;
        if constexpr (c == 0) return Bv[k].x; else if constexpr (c == 1) return Bv[k].y;
        else if constexpr (c == 2) return Bv[k].z; else return Bv[k].w;
    }
}

template<int I>
__device__ __forceinline__ void get6(const float4 (&A)[16], const float2& tA,
                                     const float2& tB, const float4 (&Bv)[16], float a[6]) {
    a[0] = getf<6*I+0>(A,tA,tB,Bv); a[1] = getf<6*I+1>(A,tA,tB,Bv);
    a[2] = getf<6*I+2>(A,tA,tB,Bv); a[3] = getf<6*I+3>(A,tA,tB,Bv);
    a[4] = getf<6*I+4>(A,tA,tB,Bv); a[5] = getf<6*I+5>(A,tA,tB,Bv);
}

// One FK joint for this lane's skeleton. Partner skeleton at lane^1; frame s+1
// at lane+2, s+2 at lane+4. All squared terms are parity-invariant.
template<int I, bool NEED_R, bool SPINE_J, bool FOOT>
__device__ __forceinline__ void joint_step(
    const float4 (&A)[16], const float2& tA, const float2& tB, const float4 (&Bv)[16],
    const float* __restrict__ off,
    const float Rp[3][3], const float pp[3],
    float Rn[3][3], float pn[3],
    float w_raw, float w_pos, float w_vel, float w_smo,
    float w_til, float w_flo, float w_con,
    float& s)
{
    float a[6];
    get6<I>(A, tA, tB, Bv, a);

    // raw-channel loss
    float dsum = 0.f;
    #pragma unroll
    for (int k = 0; k < 6; ++k) { float d = a[k] - __shfl_xor(a[k], 1); dsum += d*d; }
    s += w_raw * dsum;

    // position uses PARENT rotation
    const float ox = off[0], oy = off[1], oz = off[2];
    #pragma unroll
    for (int r = 0; r < 3; ++r)
        pn[r] = pp[r] + Rp[r][0]*ox + Rp[r][1]*oy + Rp[r][2]*oz;

    if constexpr (NEED_R) {
        float Rl[3][3];
        cont6d(a, Rl);
        if constexpr (SPINE_J) {
            float t0 = Rl[0][1] - __shfl_xor(Rl[0][1], 1);
            float t1 = Rl[1][1] - __shfl_xor(Rl[1][1], 1);
            float t2 = Rl[2][1] - __shfl_xor(Rl[2][1], 1);
            s += w_til * (t0*t0 + t1*t1 + t2*t2);
        }
        #pragma unroll
        for (int r = 0; r < 3; ++r)
            #pragma unroll
            for (int c = 0; c < 3; ++c)
                Rn[r][c] = Rp[r][0]*Rl[0][c] + Rp[r][1]*Rl[1][c] + Rp[r][2]*Rl[2][c];
    }

    float d[3];
    #pragma unroll
    for (int r = 0; r < 3; ++r) d[r] = pn[r] - __shfl_xor(pn[r], 1);
    s += w_pos * (d[0]*d[0] + d[1]*d[1] + d[2]*d[2]);

    float va = 0.f, sa = 0.f;
    float vx0 = 0.f, vy0 = 0.f, vz0 = 0.f;   // d[s+1]-d[s] components (for contact)
    {
        float d1 = __shfl_down(d[0], 2), d2 = __shfl_down(d[0], 4);
        vx0 = d1 - d[0]; va += vx0*vx0; float q = d2 - 2.f*d1 + d[0]; sa += q*q;
        d1 = __shfl_down(d[1], 2); d2 = __shfl_down(d[1], 4);
        vy0 = d1 - d[1]; va += vy0*vy0; q = d2 - 2.f*d1 + d[1]; sa += q*q;
        d1 = __shfl_down(d[2], 2); d2 = __shfl_down(d[2], 4);
        vz0 = d1 - d[2]; va += vz0*vz0; q = d2 - 2.f*d1 + d[2]; sa += q*q;
    }
    s += w_vel * va;
    s += w_smo * sa;

    if constexpr (FOOT) {
        s += w_flo * d[1]*d[1];
        float vx = __shfl_down(pn[0], 2) - pn[0];   // own-skeleton foot velocity
        float vy = __shfl_down(pn[1], 2) - pn[1];
        float vz = __shfl_down(pn[2], 2) - pn[2];
        float gx = __shfl_xor(vx, 1);                // partner = gt on even lanes
        float gy = __shfl_xor(vy, 1);
        float gz = __shfl_xor(vz, 1);
        float planted = (gx*gx + gy*gy + gz*gz < 2.5e-5f) ? 1.f : 0.f;
        s += w_con * planted * sqrtf(vx*vx + vy*vy + vz*vz);
    }
    (void)vx0; (void)vy0; (void)vz0;
}

__global__ __launch_bounds__(64, 3)
void motion_loss_kernel(const float* __restrict__ pred,
                        const float* __restrict__ targ,
                        const float* __restrict__ offs,
                        float* __restrict__ acc)
{
    const int lane = threadIdx.x;       // 0..63
    const int fid  = lane >> 1;         // frame-in-chunk 0..31
    const int par  = lane & 1;          // 0 = pred, 1 = targ
    const int bid  = blockIdx.x;
    const int b    = bid / NCHUNK;
    const int chunk= bid - b * NCHUNK;
    const int s    = chunk * CHUNK + fid;
    const int sc   = (s < kS) ? s : (kS - 1);

    const float wf = (fid < CHUNK && s     < kS) ? 1.f : 0.f;
    const float wv = (fid < CHUNK && s + 1 < kS) ? 1.f : 0.f;
    const float wa = (fid < CHUNK && s + 2 < kS) ? 1.f : 0.f;
    const float wc = (par == 0) ? wv : 0.f;

    const float w_r1  = wf * K_R1,  w_r2  = wf * K_R2,  w_rot = wf * K_ROT;
    const float w_pos = wf * K_POS, w_til = wf * K_TIL, w_flo = wf * K_FLO;
    const float w_vel = wv * K_VEL, w_smo = wa * K_SMO, w_con = wc * K_CON;

    const float* base = (par ? targ : pred) + ((size_t)b * kS + sc) * 132;
    const float4* b4 = reinterpret_cast<const float4*>(base);
    const float2* b2 = reinterpret_cast<const float2*>(base);

    // batch A: floats 0..65 (joints 0..10) — 18 independent loads, one latency exposure
    float4 A[16];
    #pragma unroll
    for (int k = 0; k < 16; ++k) A[k] = b4[k];
    float2 tA = b2[32], tB = b2[33];
    float4 Bv[16];                      // loaded after joint 7

    float loss = 0.f;

    { // joint 0: channels 0..2 only (root part 1); positions identically 0
        float d0 = getf<0>(A,tA,tB,Bv) - __shfl_xor(getf<0>(A,tA,tB,Bv), 1);
        float d1 = getf<1>(A,tA,tB,Bv) - __shfl_xor(getf<1>(A,tA,tB,Bv), 1);
        float d2 = getf<2>(A,tA,tB,Bv) - __shfl_xor(getf<2>(A,tA,tB,Bv), 1);
        loss += w_r1 * (d0*d0 + d1*d1 + d2*d2);
    }

    float R1[3][3], R3[3][3], RA[3][3], RB[3][3];
    float p1[3], p3[3], pA[3], pB[3];

    { // joint 1: parent identity; pos = offs[1] for both skeletons (pos losses cancel)
        float a[6];
        get6<1>(A, tA, tB, Bv, a);
        float dsum = 0.f;
        #pragma unroll
        for (int k = 0; k < 6; ++k) { float d = a[k] - __shfl_xor(a[k], 1); dsum += d*d; }
        loss += w_r2 * dsum;
        cont6d(a, R1);
        p1[0] = offs[3]; p1[1] = offs[4]; p1[2] = offs[5];
    }

    #define JS(I, NR, SP, FT, RP, PP, RN, PN, WRAW) \
        joint_step<I, NR, SP, FT>(A, tA, tB, Bv, offs + (I)*3, RP, PP, RN, PN, \
                                  WRAW, w_pos, w_vel, w_smo, w_til, w_flo, w_con, loss)

    JS( 2, true , true , false, R1, p1, RA, pA, w_rot);   // spine
    JS( 3, true , false, false, RA, pA, R3, p3, w_rot);
    JS( 4, true , false, false, R3, p3, RA, pA, w_rot);
    JS( 5, false, false, false, RA, pA, RB, pB, w_rot);   // leaf
    JS( 6, true , false, false, R3, p3, RA, pA, w_rot);
    JS( 7, true , false, false, RA, pA, RB, pB, w_rot);

    // batch B: floats 66..131 (joints 11..21). Barrier stops hoisting into the
    // pressure peak; ~900 cyc latency hides under joints 8..10 compute.
    __builtin_amdgcn_sched_barrier(0);
    #pragma unroll
    for (int k = 0; k < 16; ++k) Bv[k] = b4[17 + k];

    JS( 8, true , false, false, RB, pB, RA, pA, w_rot);
    JS( 9, false, false, false, RA, pA, RB, pB, w_rot);   // leaf
    JS(10, true , false, false, R3, p3, RA, pA, w_rot);   // R3 dies
    JS(11, true , false, false, RA, pA, RB, pB, w_rot);
    JS(12, true , false, false, RB, pB, RA, pA, w_rot);
    JS(13, false, false, false, RA, pA, RB, pB, w_rot);   // leaf
    JS(14, true , false, false, R1, p1, RA, pA, w_rot);
    JS(15, true , false, false, RA, pA, RB, pB, w_rot);
    JS(16, true , false, false, RB, pB, RA, pA, w_rot);
    JS(17, true , false, false, RA, pA, RB, pB, w_rot);
    JS(18, false, false, true , RB, pB, RA, pA, w_rot);   // FOOT leaf
    JS(19, true , false, false, R1, p1, RA, pA, w_rot);   // R1 dies
    JS(20, true , false, false, RA, pA, RB, pB, w_rot);
    JS(21, false, false, true , RB, pB, RA, pA, w_rot);   // FOOT leaf
    #undef JS

    // single pre-scaled accumulator: one butterfly + one atomic per wave
    float v = loss;
    #pragma unroll
    for (int o = 32; o > 0; o >>= 1) v += __shfl_xor(v, o);
    if (lane == 0) atomicAdd(&acc[bid & (NSLOT - 1)], v);
}

__global__ void finalize_kernel(const float* __restrict__ acc, float* __restrict__ out) {
    float v = acc[threadIdx.x];
    #pragma unroll
    for (int o = 32; o > 0; o >>= 1) v += __shfl_xor(v, o);
    if (threadIdx.x == 0) out[0] = v;
}

} // namespace

extern "C" void kernel_launch(void* const* d_in, const int* in_sizes, int n_in,
                              void* d_out, int out_size, void* d_ws, size_t ws_size,
                              hipStream_t stream) {
    const float* pred = (const float*)d_in[0];
    const float* targ = (const float*)d_in[1];
    const float* offs = (const float*)d_in[2];
    float* acc = (float*)d_ws;

    hipMemsetAsync(acc, 0, NSLOT * sizeof(float), stream);
    motion_loss_kernel<<<dim3(kB * NCHUNK), dim3(64), 0, stream>>>(pred, targ, offs, acc);
    finalize_kernel<<<1, 64, 0, stream>>>(acc, (float*)d_out);
}